// Round 4
// baseline (335.520 us; speedup 1.0000x reference)
//
#include <hip/hip_runtime.h>

// Problem constants (fixed by the reference file)
#define NN   1024      // nodes
#define FD   128       // input features
#define DD1  64        // hidden dim after W1
#define DD2  16        // edge-MLP dim
#define MAXM 16384     // max directed edges (2 * E_HALF)
#define DSTRIDE 64     // fixed adjacency stride (max degree << 64)
#define ALPHA_C 0.1f
#define NBLK 256

// Persistent device scratch (rebuilt from inputs every launch; deterministic)
__device__ __attribute__((aligned(16))) unsigned short g_T[NN * NN]; // (u,v)->e+1, 0 none
__device__ int   g_deg[NN];
__device__ int   g_adj_e[NN * DSTRIDE]; // fixed-stride adjacency: edge id (u->v)
__device__ int   g_adj_v[NN * DSTRIDE]; // fixed-stride adjacency: neighbor v (sorted)
__device__ float g_dinv[NN];            // 1/sqrt(deg+1)
__device__ float g_x0[NN * DD1];        // feat@W1+b1
__device__ float g_x1[NN * DD1];
__device__ float g_x2[NN * DD1];        // final propagated features
__device__ float g_xe[MAXM * DD2];      // per-directed-edge MLP outputs
__device__ float g_mul[MAXM * DD2];

// Hand-rolled grid barrier (padded to separate cachelines)
__device__ int g_arrive[16];
__device__ int g_gen[16];

__device__ __forceinline__ void gbar() {
    __syncthreads();
    if (threadIdx.x == 0) {
        int gen = __hip_atomic_load(&g_gen[0], __ATOMIC_RELAXED, __HIP_MEMORY_SCOPE_AGENT);
        if (__hip_atomic_fetch_add(&g_arrive[0], 1, __ATOMIC_ACQ_REL,
                                   __HIP_MEMORY_SCOPE_AGENT) == NBLK - 1) {
            __hip_atomic_store(&g_arrive[0], 0, __ATOMIC_RELAXED, __HIP_MEMORY_SCOPE_AGENT);
            __hip_atomic_fetch_add(&g_gen[0], 1, __ATOMIC_ACQ_REL, __HIP_MEMORY_SCOPE_AGENT);
        } else {
            while (__hip_atomic_load(&g_gen[0], __ATOMIC_ACQUIRE,
                                     __HIP_MEMORY_SCOPE_AGENT) == gen)
                __builtin_amdgcn_s_sleep(8);
        }
    }
    __syncthreads();
}

__device__ __forceinline__ void prop_phase(int tid, const float* __restrict__ xin,
                                           float* __restrict__ xout) {
    int u = tid >> 6;
    int d = tid & 63;
    int beg = u * DSTRIDE;
    int end = beg + g_deg[u];
    float acc = 0.f;
    for (int j = beg; j < end; ++j) {
        int v = g_adj_v[j];
        acc += g_dinv[v] * xin[v * DD1 + d];
    }
    float du = g_dinv[u];
    float ah = du * (acc + du * xin[u * DD1 + d]);   // includes self-loop
    xout[u * DD1 + d] = (1.0f - ALPHA_C) * ah + ALPHA_C * g_x0[u * DD1 + d];
}

// One cooperative kernel: 256 blocks x 256 threads (65536 threads, 1 block/CU).
__global__ void fused_k(const float* __restrict__ feat,
                        const float* __restrict__ W1,  const float* __restrict__ b1,
                        const float* __restrict__ Wm1, const float* __restrict__ bm1,
                        const float* __restrict__ Wm2, const float* __restrict__ bm2,
                        const float* __restrict__ W3,  const float* __restrict__ b3,
                        const int* __restrict__ ei0,   const int* __restrict__ ei1,
                        const int* __restrict__ pos,   float* __restrict__ out,
                        int M, int P) {
    const int tid = blockIdx.x * blockDim.x + threadIdx.x;   // 0..65535
    const int nthr = NBLK * 256;

    // ---- Phase A: zero g_T/g_deg + x0 = feat@W1 + b1 -------------------
    {
        int4* T4 = (int4*)g_T;                  // 2 MB -> 131072 int4
        T4[tid] = make_int4(0, 0, 0, 0);
        T4[tid + nthr] = make_int4(0, 0, 0, 0);
        if (tid < NN) g_deg[tid] = 0;
        int n = tid >> 6, d = tid & 63;
        const float* fr = feat + n * FD;
        float acc = b1[d];
        #pragma unroll 8
        for (int k = 0; k < FD; ++k) acc += fr[k] * W1[k * DD1 + d];
        g_x0[tid] = acc;                                     // tid == n*64+d
    }
    gbar();

    // ---- Phase B: edge table + degrees ---------------------------------
    for (int e = tid; e < M; e += nthr) {
        int a = ei0[e], b = ei1[e];
        g_T[a * NN + b] = (unsigned short)(e + 1);  // unique (a,b) -> race-free
        atomicAdd(&g_deg[a], 1);
    }
    gbar();

    // ---- Phase C: dinv + fixed-stride adjacency (ballot compaction) ----
    {
        if (tid < NN) g_dinv[tid] = rsqrtf((float)(g_deg[tid] + 1));
        int u = tid >> 6;                  // 1024 waves == 1024 rows
        int lane = tid & 63;
        unsigned short eid[16];
        #pragma unroll
        for (int i = 0; i < 16; ++i) eid[i] = g_T[u * NN + i * 64 + lane];
        int base = u * DSTRIDE;
        int cnt = 0;
        #pragma unroll
        for (int i = 0; i < 16; ++i) {
            unsigned long long m = __ballot(eid[i] != 0);
            if (eid[i] != 0) {
                int p = __popcll(m & ((1ULL << lane) - 1ULL));
                g_adj_e[base + cnt + p] = (int)eid[i] - 1;
                g_adj_v[base + cnt + p] = i * 64 + lane;
            }
            cnt += __popcll(m);
        }
    }
    gbar();

    // ---- Phase D/E: two propagation rounds -----------------------------
    prop_phase(tid, g_x0, g_x1);
    gbar();
    prop_phase(tid, g_x1, g_x2);
    gbar();

    // ---- Phase F: edge MLP (xe, mul per directed edge) -----------------
    for (int t = tid; t < M * 32; t += nthr) {
        int e = t >> 5;
        int j = t & 31;
        int m = j & 15;
        const float* W = (j < 16) ? Wm1 : Wm2;
        const float* B = (j < 16) ? bm1 : bm2;
        float*       O = (j < 16) ? g_xe : g_mul;
        int a = ei0[e], b = ei1[e];
        const float* xa = g_x2 + a * DD1;
        const float* xb = g_x2 + b * DD1;
        float acc = B[m];
        #pragma unroll 8
        for (int k = 0; k < DD1; ++k) acc += xa[k] * W[k * DD2 + m];
        #pragma unroll 8
        for (int k = 0; k < DD1; ++k) acc += xb[k] * W[(DD1 + k) * DD2 + m];
        O[e * DD2 + m] = acc;
    }
    gbar();

    // ---- Phase G: per-query-pair phase, 16 lanes per pair --------------
    {
        int lane = threadIdx.x & 63;
        int grp  = lane >> 4;              // 4 pair-groups per wave
        int m    = lane & 15;
        int wave = tid >> 6;
        int p = wave * 4 + grp;            // 65536 threads == P*16 tasks
        if (p < P) {
            int u = pos[2 * p], w = pos[2 * p + 1];

            // xx = x2[u] . x2[w]  (16-lane split + reduce)
            const float* xu = g_x2 + u * DD1;
            const float* xw = g_x2 + w * DD1;
            float xx = 0.f;
            #pragma unroll
            for (int d = m; d < DD1; d += 16) xx += xu[d] * xw[d];
            #pragma unroll
            for (int o = 8; o; o >>= 1) xx += __shfl_xor(xx, o);

            // common-neighbor products: lane m prefetches neighbor j0+m
            float p0 = 0.f, p1 = 0.f;
            bool found = false;
            int beg = u * DSTRIDE;
            int end = beg + g_deg[u];
            for (int j0 = beg; j0 < end; j0 += 16) {
                int j = j0 + m;
                int t_vw = 0, e_uv = 0, e_wv = 0, e_vu = 0;
                if (j < end) {
                    int v  = g_adj_v[j];
                    e_uv   = g_adj_e[j];
                    t_vw   = (int)g_T[v * NN + w];
                    e_vu   = (int)g_T[v * NN + u] - 1;
                    e_wv   = (int)g_T[w * NN + v] - 1;   // valid iff t_vw > 0
                }
                unsigned long long mask = __ballot(t_vw > 0);
                unsigned long long gm = (mask >> (grp * 16)) & 0xFFFFULL;
                if (gm) found = true;
                while (gm) {
                    int k = __ffsll(gm) - 1;
                    gm &= gm - 1;
                    int src = grp * 16 + k;
                    int a0 = __shfl(e_uv, src);
                    int b0 = __shfl(t_vw, src) - 1;
                    int a1 = __shfl(e_wv, src);
                    int b1 = __shfl(e_vu, src);
                    p0 += g_xe[a0 * DD2 + m] * g_mul[b0 * DD2 + m];
                    p1 += g_xe[a1 * DD2 + m] * g_mul[b1 * DD2 + m];
                }
            }

            int s_uw = (int)g_T[u * NN + w];
            float res = xx;
            if (found || s_uw > 0) {
                float se = (s_uw > 0) ? 1.0f : 0.0f;
                float base = b3[m] + se * W3[16 * DD2 + m];
                float y0 = base, y1 = base;
                #pragma unroll
                for (int k = 0; k < DD2; ++k) {
                    float wk  = W3[k * DD2 + m];
                    float p0k = __shfl(p0, grp * 16 + k);
                    float p1k = __shfl(p1, grp * 16 + k);
                    y0 += p0k * wk;
                    y1 += p1k * wk;
                }
                float ef = y0 * y1;
                #pragma unroll
                for (int o = 8; o; o >>= 1) ef += __shfl_xor(ef, o);
                res += ef;
            }
            if (m == 0) out[p] = res;
        }
    }
}

// ----------------------------------------------------------------
extern "C" void kernel_launch(void* const* d_in, const int* in_sizes, int n_in,
                              void* d_out, int out_size, void* d_ws, size_t ws_size,
                              hipStream_t stream) {
    const float* feat = (const float*)d_in[0];
    const float* W1   = (const float*)d_in[1];
    const float* b1   = (const float*)d_in[2];
    const float* Wm1  = (const float*)d_in[3];
    const float* bm1  = (const float*)d_in[4];
    const float* Wm2  = (const float*)d_in[5];
    const float* bm2  = (const float*)d_in[6];
    const float* W3   = (const float*)d_in[7];
    const float* b3   = (const float*)d_in[8];
    const int*   ei   = (const int*)d_in[9];
    const int*   pos  = (const int*)d_in[10];
    float* out = (float*)d_out;

    int M = in_sizes[9] / 2;       // directed edges
    int P = in_sizes[10] / 2;      // query pairs
    const int* ei0 = ei;
    const int* ei1 = ei + M;

    void* args[] = { (void*)&feat, (void*)&W1, (void*)&b1,
                     (void*)&Wm1, (void*)&bm1, (void*)&Wm2, (void*)&bm2,
                     (void*)&W3, (void*)&b3,
                     (void*)&ei0, (void*)&ei1, (void*)&pos,
                     (void*)&out, (void*)&M, (void*)&P };
    hipLaunchCooperativeKernel((const void*)fused_k, dim3(NBLK), dim3(256),
                               args, 0, stream);
}

// Round 5
// 84.528 us; speedup vs baseline: 3.9694x; 3.9694x over previous
//
#include <hip/hip_runtime.h>

// Problem constants (fixed by the reference file)
#define NN   1024      // nodes
#define FD   128       // input features
#define DD1  64        // hidden dim after W1
#define DD2  16        // edge-MLP dim
#define MAXM 16384     // max directed edges (2 * E_HALF)
#define DSTRIDE 64     // fixed adjacency stride (max degree << 64)
#define ALPHA_C 0.1f

// Persistent device scratch (rebuilt from inputs every launch; deterministic)
__device__ __attribute__((aligned(16))) unsigned short g_T[NN * NN]; // (u,v)->e+1, 0 none
__device__ int   g_deg[NN];
__device__ int   g_adj_e[NN * DSTRIDE]; // fixed-stride adjacency: edge id (u->v)
__device__ int   g_adj_v[NN * DSTRIDE]; // fixed-stride adjacency: neighbor v (sorted)
__device__ float g_x0[NN * DD1];        // feat@W1+b1
__device__ float g_x1[NN * DD1];
__device__ float g_x2[NN * DD1];        // final propagated features
__device__ float g_xe[MAXM * DD2];      // per-directed-edge MLP outputs
__device__ float g_mul[MAXM * DD2];

// ---- K1: zero g_T/g_deg + x0 = feat@W1 + b1 (256 x 256) ----------------
__global__ void init_k(const float* __restrict__ feat,
                       const float* __restrict__ W1,
                       const float* __restrict__ b1) {
    int tid = blockIdx.x * blockDim.x + threadIdx.x;   // 0..65535
    int4* T4 = (int4*)g_T;                             // 2 MB -> 131072 int4
    int4 z = make_int4(0, 0, 0, 0);
    T4[tid] = z;
    T4[tid + 65536] = z;
    if (tid < NN) g_deg[tid] = 0;
    int n = tid >> 6, d = tid & 63;
    const float* fr = feat + n * FD;
    float acc = b1[d];
    #pragma unroll 8
    for (int k = 0; k < FD; ++k) acc += fr[k] * W1[k * DD1 + d];
    g_x0[tid] = acc;                                   // tid == n*64+d
}

// ---- K2: edge table + degrees ------------------------------------------
__global__ void build_k(const int* __restrict__ ei0, const int* __restrict__ ei1, int M) {
    int e = blockIdx.x * blockDim.x + threadIdx.x;
    if (e < M) {
        int a = ei0[e], b = ei1[e];
        g_T[a * NN + b] = (unsigned short)(e + 1);     // unique (a,b) -> race-free
        atomicAdd(&g_deg[a], 1);
    }
}

// ---- K3: row compaction (deterministic, ballot) + propagation round 1 --
// one wave per node u; lane = channel d
__global__ void csrprop_k() {
    int u = blockIdx.x;
    int lane = threadIdx.x;                 // blockDim = 64
    const unsigned short* row = g_T + u * NN;
    int base = u * DSTRIDE;
    int cnt = 0;
    #pragma unroll
    for (int i = 0; i < 16; ++i) {
        int eid = (int)row[i * 64 + lane];
        unsigned long long mk = __ballot(eid != 0);
        if (eid != 0) {
            int p = __popcll(mk & ((1ULL << lane) - 1ULL));
            g_adj_e[base + cnt + p] = eid - 1;
            g_adj_v[base + cnt + p] = i * 64 + lane;
        }
        cnt += __popcll(mk);
    }
    // propagation round 1 (adj just written by this wave; same-CU L1 visible)
    float x0u = g_x0[u * DD1 + lane];
    float acc = 0.f;
    for (int j = 0; j < cnt; ++j) {
        int v = g_adj_v[base + j];                     // wave-broadcast load
        float dv = rsqrtf((float)(g_deg[v] + 1));
        acc += dv * g_x0[v * DD1 + lane];
    }
    float du = rsqrtf((float)(cnt + 1));
    float ah = du * (acc + du * x0u);                  // includes self-loop
    g_x1[u * DD1 + lane] = (1.0f - ALPHA_C) * ah + ALPHA_C * x0u;
}

// ---- K4: propagation round 2 -------------------------------------------
__global__ void prop2_k() {
    int u = blockIdx.x;
    int lane = threadIdx.x;                 // blockDim = 64
    int cnt = g_deg[u];
    int base = u * DSTRIDE;
    float acc = 0.f;
    for (int j = 0; j < cnt; ++j) {
        int v = g_adj_v[base + j];
        float dv = rsqrtf((float)(g_deg[v] + 1));
        acc += dv * g_x1[v * DD1 + lane];
    }
    float du = rsqrtf((float)(cnt + 1));
    float x1u = g_x1[u * DD1 + lane];
    float ah = du * (acc + du * x1u);
    g_x2[u * DD1 + lane] = (1.0f - ALPHA_C) * ah + ALPHA_C * g_x0[u * DD1 + lane];
}

// ---- K5: edge MLP, both directions per undirected edge -----------------
// ei second half is the exact swap of the first half: rev(e) = e + EHalf.
__global__ void mlp_k(const int* __restrict__ ei0, const int* __restrict__ ei1,
                      const float* __restrict__ Wm1, const float* __restrict__ bm1,
                      const float* __restrict__ Wm2, const float* __restrict__ bm2,
                      int EHalf) {
    int t = blockIdx.x * blockDim.x + threadIdx.x;
    if (t >= EHalf * DD2) return;
    int e = t >> 4;
    int m = t & 15;
    int a = ei0[e], b = ei1[e];
    const float* xa = g_x2 + a * DD1;
    const float* xb = g_x2 + b * DD1;
    float xef = bm1[m], xer = bm1[m], mf = bm2[m], mr = bm2[m];
    #pragma unroll 4
    for (int k = 0; k < DD1; ++k) {
        float va = xa[k], vb = xb[k];
        float w1l = Wm1[k * DD2 + m], w1h = Wm1[(DD1 + k) * DD2 + m];
        float w2l = Wm2[k * DD2 + m], w2h = Wm2[(DD1 + k) * DD2 + m];
        xef += va * w1l + vb * w1h;
        xer += vb * w1l + va * w1h;
        mf  += va * w2l + vb * w2h;
        mr  += vb * w2l + va * w2h;
    }
    g_xe [e * DD2 + m]            = xef;
    g_xe [(e + EHalf) * DD2 + m]  = xer;
    g_mul[e * DD2 + m]            = mf;
    g_mul[(e + EHalf) * DD2 + m]  = mr;
}

// ---- K6: per-query-pair phase, 16 lanes per pair -----------------------
__global__ void pair_k(const int* __restrict__ pos,
                       const float* __restrict__ W3, const float* __restrict__ b3,
                       float* __restrict__ out, int P) {
    int lane = threadIdx.x & 63;
    int grp  = lane >> 4;                  // 4 pair-groups per wave
    int m    = lane & 15;
    int wave = (blockIdx.x * blockDim.x + threadIdx.x) >> 6;
    int p = wave * 4 + grp;
    if (p >= P) return;
    int u = pos[2 * p], w = pos[2 * p + 1];

    // xx = x2[u] . x2[w]  (16-lane split + reduce)
    const float* xu = g_x2 + u * DD1;
    const float* xw = g_x2 + w * DD1;
    float xx = 0.f;
    #pragma unroll
    for (int d = m; d < DD1; d += 16) xx += xu[d] * xw[d];
    #pragma unroll
    for (int o = 8; o; o >>= 1) xx += __shfl_xor(xx, o);

    // common-neighbor products; only ONE gather (t_vw) in the hot path
    float p0 = 0.f, p1 = 0.f;
    bool found = false;
    int cnt = g_deg[u];
    int base = u * DSTRIDE;
    for (int j0 = 0; j0 < cnt; j0 += 16) {
        int j = j0 + m;
        int v = 0, e_uv = 0, t_vw = 0;
        if (j < cnt) {
            v    = g_adj_v[base + j];
            e_uv = g_adj_e[base + j];
            t_vw = (int)g_T[v * NN + w];
        }
        unsigned long long mask = __ballot(t_vw > 0);
        unsigned long long gm = (mask >> (grp * 16)) & 0xFFFFULL;
        if (gm) found = true;
        while (gm) {   // rare: E[common neighbors] ~ 0.25 per pair
            int k = __ffsll(gm) - 1;
            gm &= gm - 1;
            int src = grp * 16 + k;
            int vk = __shfl(v, src);
            int a0 = __shfl(e_uv, src);
            int b0 = __shfl(t_vw, src) - 1;
            int a1 = (int)g_T[w * NN + vk] - 1;   // broadcast load (undirected => exists)
            int b1 = (int)g_T[vk * NN + u] - 1;   // broadcast load
            p0 += g_xe[a0 * DD2 + m] * g_mul[b0 * DD2 + m];
            p1 += g_xe[a1 * DD2 + m] * g_mul[b1 * DD2 + m];
        }
    }

    int s_uw = (int)g_T[u * NN + w];
    float res = xx;
    if (found || s_uw > 0) {
        float se = (s_uw > 0) ? 1.0f : 0.0f;
        float base3 = b3[m] + se * W3[16 * DD2 + m];
        float y0 = base3, y1 = base3;
        #pragma unroll
        for (int k = 0; k < DD2; ++k) {
            float wk  = W3[k * DD2 + m];
            float p0k = __shfl(p0, grp * 16 + k);
            float p1k = __shfl(p1, grp * 16 + k);
            y0 += p0k * wk;
            y1 += p1k * wk;
        }
        float ef = y0 * y1;
        #pragma unroll
        for (int o = 8; o; o >>= 1) ef += __shfl_xor(ef, o);
        res += ef;
    }
    if (m == 0) out[p] = res;
}

// ----------------------------------------------------------------
extern "C" void kernel_launch(void* const* d_in, const int* in_sizes, int n_in,
                              void* d_out, int out_size, void* d_ws, size_t ws_size,
                              hipStream_t stream) {
    const float* feat = (const float*)d_in[0];
    const float* W1   = (const float*)d_in[1];
    const float* b1   = (const float*)d_in[2];
    const float* Wm1  = (const float*)d_in[3];
    const float* bm1  = (const float*)d_in[4];
    const float* Wm2  = (const float*)d_in[5];
    const float* bm2  = (const float*)d_in[6];
    const float* W3   = (const float*)d_in[7];
    const float* b3   = (const float*)d_in[8];
    const int*   ei   = (const int*)d_in[9];
    const int*   pos  = (const int*)d_in[10];
    float* out = (float*)d_out;

    int M  = in_sizes[9] / 2;      // directed edges
    int EH = M / 2;                // undirected edges (second half of ei = swapped)
    int P  = in_sizes[10] / 2;     // query pairs
    const int* ei0 = ei;
    const int* ei1 = ei + M;

    init_k<<<256, 256, 0, stream>>>(feat, W1, b1);
    build_k<<<(M + 255) / 256, 256, 0, stream>>>(ei0, ei1, M);
    csrprop_k<<<NN, 64, 0, stream>>>();
    prop2_k<<<NN, 64, 0, stream>>>();
    mlp_k<<<(EH * DD2 + 255) / 256, 256, 0, stream>>>(ei0, ei1, Wm1, bm1, Wm2, bm2, EH);
    pair_k<<<(P * 16 + 255) / 256, 256, 0, stream>>>(pos, W3, b3, out, P);
}